// Round 7
// baseline (126.397 us; speedup 1.0000x reference)
//
#include <hip/hip_runtime.h>
#include <stdint.h>

#define CIN   4
#define LEN   2048
#define HN    256
#define GL    24
#define LOUT  2025          // LEN - GL + 1
#define XP    2080          // padded LDS row stride in halfwords (mult of 8, >= 2048+32)

typedef short  s16x8 __attribute__((ext_vector_type(8)));
typedef float  f32x4 __attribute__((ext_vector_type(4)));

// final pool buffer: [b][0..255]=maxPool, [b][256..511]=avgPool
__device__ float g_pool[256 * 512];            // 512 KB, fully overwritten each run

static __device__ __forceinline__ uint16_t f2bf(float f) {
    union { float f; uint32_t u; } v; v.f = f;
    uint32_t u = v.u;
    return (uint16_t)((u + 0x7FFFu + ((u >> 16) & 1u)) >> 16);   // RNE
}

// Build the A fragment for phase p from an 8-dword window dd[0..7].
// Even p: direct dword selection; odd p: alignbit-shift by 16 bits (the 7
// unique shifted dwords are CSE'd across the 4 odd phases).
#define MKFRAG(dd, p) \
    ({ uint32_t f0_, f1_, f2_, f3_; \
       if (((p) & 1) == 0) { \
           f0_ = dd[(p)/2];   f1_ = dd[(p)/2+1]; \
           f2_ = dd[(p)/2+2]; f3_ = dd[(p)/2+3]; \
       } else { \
           f0_ = __builtin_amdgcn_alignbit(dd[((p)+1)/2],   dd[((p)-1)/2],   16); \
           f1_ = __builtin_amdgcn_alignbit(dd[((p)+1)/2+1], dd[((p)-1)/2+1], 16); \
           f2_ = __builtin_amdgcn_alignbit(dd[((p)+1)/2+2], dd[((p)-1)/2+2], 16); \
           f3_ = __builtin_amdgcn_alignbit(dd[((p)+1)/2+3], dd[((p)-1)/2+3], 16); \
       } \
       uint4 fu_ = {f0_, f1_, f2_, f3_}; __builtin_bit_cast(s16x8, fu_); })

// issue the 6 ds_read_b128 for window j into D (consumed one window later)
static __device__ __forceinline__ void loadW(
    uint32_t (&D)[3][8], const uint16_t* xs, const int (&abase)[3], int j)
{
    #pragma unroll
    for (int ks = 0; ks < 3; ++ks) {
        const uint4 r0 = *(const uint4*)&xs[abase[ks] + 128 * j];
        const uint4 r1 = *(const uint4*)&xs[abase[ks] + 128 * j + 8];
        D[ks][0] = r0.x; D[ks][1] = r0.y; D[ks][2] = r0.z; D[ks][3] = r0.w;
        D[ks][4] = r1.x; D[ks][5] = r1.y; D[ks][6] = r1.z; D[ks][7] = r1.w;
    }
}

// process one 128-position window for 64 nodes: 8 phases x (3 K-steps x
// 4 node-subtiles) = 96 MFMA in 4 independent depth-3 chains per phase.
// Immediate relu-fold. tail (wave-uniform) masks tpos >= 2025 at j==15.
static __device__ __forceinline__ void procW(
    const uint32_t (&D)[3][8], const s16x8 (&bfrag)[4][3],
    const float (&negb)[4], bool tail, int q,
    float (&rawmax)[4], float (&sums)[4])
{
    const f32x4 fzero = {0.f, 0.f, 0.f, 0.f};
    #pragma unroll
    for (int p = 0; p < 8; ++p) {
        s16x8 a0 = MKFRAG(D[0], p);
        s16x8 a1 = MKFRAG(D[1], p);
        s16x8 a2 = MKFRAG(D[2], p);
        f32x4 acc[4];
        #pragma unroll
        for (int s = 0; s < 4; ++s)
            acc[s] = __builtin_amdgcn_mfma_f32_16x16x32_bf16(a0, bfrag[s][0], fzero, 0, 0, 0);
        #pragma unroll
        for (int s = 0; s < 4; ++s)
            acc[s] = __builtin_amdgcn_mfma_f32_16x16x32_bf16(a1, bfrag[s][1], acc[s], 0, 0, 0);
        #pragma unroll
        for (int s = 0; s < 4; ++s)
            acc[s] = __builtin_amdgcn_mfma_f32_16x16x32_bf16(a2, bfrag[s][2], acc[s], 0, 0, 0);

        // maxPool = max(0, b + max_t raw) -> track raw max (no clamp needed)
        // avgPool uses t = max(raw, -b), summed in a small tree.
        if (!tail) {
            #pragma unroll
            for (int s = 0; s < 4; ++s) {
                const f32x4 a = acc[s];
                float t0 = fmaxf(a[0], negb[s]), t1 = fmaxf(a[1], negb[s]);
                float t2 = fmaxf(a[2], negb[s]), t3 = fmaxf(a[3], negb[s]);
                sums[s] += (t0 + t1) + (t2 + t3);
                rawmax[s] = fmaxf(fmaxf(rawmax[s], a[0]), a[1]);   // -> v_max3
                rawmax[s] = fmaxf(fmaxf(rawmax[s], a[2]), a[3]);
            }
        } else {                            // j==15: mask tpos >= 2025
            #pragma unroll
            for (int s = 0; s < 4; ++s) {
                const f32x4 a = acc[s];
                #pragma unroll
                for (int r = 0; r < 4; ++r) {
                    int tpos = p + 128 * 15 + 32 * q + 8 * r;
                    float t = (tpos < LOUT) ? fmaxf(a[r], negb[s])
                                            : negb[s];   // contributes exactly 0 after +b
                    sums[s]   += t;
                    rawmax[s]  = fmaxf(rawmax[s], t);
                }
            }
        }
    }
}

// ---------------------------------------------------------------------------
// Kernel 1: per-sample conv1d (bf16 MFMA) + bias/relu + max/avg pool, fused.
// grid = 256 blocks (1 sample), 512 threads = 8 waves.
// WIDE-TILE RESTRUCTURE (s=4): wave (ng = wid&3, jh = wid>>2) owns 64 nodes
// [64ng, 64ng+64) for the 8 windows j in [8jh, 8jh+8). Per phase the MFMA
// group is 4 independent depth-3 chains (vs 2 in round 6) and each window
// load (6 ds_read_b128) now feeds 96 MFMA (vs 48) -> 2x the latency-hiding
// ILP and half the LDS/frag overhead at identical total MFMA count.
// Registers: d-windows 48 (depth-1 pipeline) + bfrag 48 + acc ~32 + misc
// ~ 200/wave; amdgpu_waves_per_eu(2,2) pins the 256-reg budget (r5 lesson:
// without the pin the allocator shrinks to 128 and spills; r2/r5 evidence).
// Positions: t = 128j + 32q + 8r + p. Pooling is order-invariant -> exact.
// ---------------------------------------------------------------------------
__global__ __launch_bounds__(512) __attribute__((amdgpu_waves_per_eu(2, 2)))
void conv_pool_kernel(
    const float* __restrict__ x, const float* __restrict__ wConv,
    const float* __restrict__ wRect)
{
    __shared__ uint16_t xs[CIN * XP];          // 16640 B, bf16 x for this sample
    __shared__ float pmax_l[2][HN];            // per-jh partial max
    __shared__ float psum_l[2][HN];            // per-jh partial sum

    const int tid  = threadIdx.x;
    const int b    = blockIdx.x;
    const int lane = tid & 63;
    const int wid  = tid >> 6;                 // 0..7
    const int ng   = wid & 3;                  // node group: nodes 64ng..64ng+63
    const int jh   = wid >> 2;                 // window half: j in [8jh, 8jh+8)
    const int n    = lane & 15;                // MFMA row (A) / col (B,C)
    const int q    = lane >> 4;                // quad 0..3

    // ---- stage x[b] -> LDS as bf16 (coalesced float4 loads) ----
    const float* xb = x + (size_t)b * (CIN * LEN);
    #pragma unroll
    for (int it = 0; it < 4; ++it) {
        int i = (tid + it * 512) * 4;          // 0..8188 step 4
        float4 v = *(const float4*)(xb + i);
        int c = i >> 11, off = i & 2047;
        uint64_t pk =  (uint64_t)f2bf(v.x)
                    | ((uint64_t)f2bf(v.y) << 16)
                    | ((uint64_t)f2bf(v.z) << 32)
                    | ((uint64_t)f2bf(v.w) << 48);
        *(uint64_t*)&xs[c * XP + off] = pk;
    }
    // zero the pad tail [2048, 2080) of each row
    if (tid < 64) {
        int c = tid >> 4, o = (tid & 15) * 2;
        *(uint32_t*)&xs[c * XP + 2048 + o] = 0u;
    }

    // ---- resident B fragments (weights) + bias, straight from global ----
    // B[k][n]: n -> node h0+n ; quad q -> k-8block jb = 4*ks + q
    // jb -> (c = jb/3, g0 = 8*(jb%3)); w[h][c][g0..g0+8) contiguous fp32.
    s16x8 bfrag[4][3];
    float negb[4];
    #pragma unroll
    for (int s = 0; s < 4; ++s) {
        int h = ng * 64 + s * 16 + n;
        negb[s] = -wRect[h];
        #pragma unroll
        for (int ks = 0; ks < 3; ++ks) {
            int jb = ks * 4 + q;
            const float* wp_ = wConv + h * (CIN * GL) + jb * 8;
            float4 w0 = *(const float4*)(wp_);
            float4 w1 = *(const float4*)(wp_ + 4);
            s16x8 f;
            f[0]=(short)f2bf(w0.x); f[1]=(short)f2bf(w0.y);
            f[2]=(short)f2bf(w0.z); f[3]=(short)f2bf(w0.w);
            f[4]=(short)f2bf(w1.x); f[5]=(short)f2bf(w1.y);
            f[6]=(short)f2bf(w1.z); f[7]=(short)f2bf(w1.w);
            bfrag[s][ks] = f;
        }
    }

    // per-lane A base (halfword index): all terms mult of 8 -> 16B aligned
    int abase[3];
    #pragma unroll
    for (int ks = 0; ks < 3; ++ks) {
        int jb = ks * 4 + q;
        int c = jb / 3, g0 = (jb % 3) * 8;
        abase[ks] = c * XP + g0 + 8 * n;
    }

    __syncthreads();

    float rawmax[4] = {-1e30f, -1e30f, -1e30f, -1e30f};
    float sums[4]   = {0.f, 0.f, 0.f, 0.f};

    // ---- depth-1 pipelined 8-window loop (static dA/dB naming) ----
    const int j0 = jh * 8;
    uint32_t dA[3][8], dB[3][8];
    loadW(dA, xs, abase, j0);
    #pragma unroll 1
    for (int jj = 0; jj < 8; jj += 2) {
        loadW(dB, xs, abase, j0 + jj + 1);                     // prefetch odd window
        procW(dA, bfrag, negb, false, q, rawmax, sums);        // j = j0+jj (even, <=14)
        int jn = (jj + 2 < 8) ? j0 + jj + 2 : 15;              // clamp: harmless re-read
        loadW(dA, xs, abase, jn);                              // prefetch next even
        procW(dB, bfrag, negb, (jh == 1) && (jj == 6), q, rawmax, sums);  // j = j0+jj+1
    }

    // ---- cross-quad reduce (lanes n, n+16, n+32, n+48), partials to LDS ----
    #pragma unroll
    for (int s = 0; s < 4; ++s) {
        float m  = rawmax[s], sm = sums[s];
        m  = fmaxf(m, __shfl_xor(m, 16, 64));  sm += __shfl_xor(sm, 16, 64);
        m  = fmaxf(m, __shfl_xor(m, 32, 64));  sm += __shfl_xor(sm, 32, 64);
        if (q == 0) {
            int h = ng * 64 + s * 16 + n;
            pmax_l[jh][h] = m;
            psum_l[jh][h] = sm;
        }
    }
    __syncthreads();

    // ---- combine the two window-halves and write the final pool row ----
    if (tid < HN) {
        float m   = fmaxf(pmax_l[0][tid], pmax_l[1][tid]);
        float sm  = psum_l[0][tid] + psum_l[1][tid];
        float bia = wRect[tid];
        // maxPool = max(0, b + max_t raw) ; avgPool = (sum_t + 2048*b)/2025
        g_pool[(size_t)b * 512 + tid]       = fmaxf(m + bia, 0.f);
        g_pool[(size_t)b * 512 + 256 + tid] = (sm + 2048.f * bia) * (1.0f / 2025.0f);
    }
}

// ---------------------------------------------------------------------------
// Kernel 2: fp32 MLP. hid = relu(pool @ wH + bH); out = 0.5*hid@wNeu + bias.
// grid = 256 blocks: 8 output-groups (64 outs) x 32 sample-groups (8 samples).
// 256 threads: o = og*64 + (tid&63); wave wv handles samples wv*2, wv*2+1.
// Partial dot wave-reduced, atomicAdd into zeroed d_out.
// ---------------------------------------------------------------------------
__global__ __launch_bounds__(256, 4) void mlp_kernel(
    const float* __restrict__ wH, const float* __restrict__ bH,
    const float* __restrict__ wNeu, const float* __restrict__ wNeuB,
    float* __restrict__ out)
{
    __shared__ float pl[8][512];               // 16 KB

    const int tid = threadIdx.x;
    const int og  = blockIdx.x & 7;
    const int bg  = blockIdx.x >> 3;
    const int o   = og * 64 + (tid & 63);
    const int wv  = tid >> 6;                  // wave id -> samples wv*2 + {0,1}

    const float* ps = g_pool + (size_t)bg * 8 * 512;
    #pragma unroll
    for (int it = 0; it < 4; ++it) {
        int i = (tid + it * 256) * 4;          // 0..4095
        *(float4*)&pl[0][i] = *(const float4*)(ps + i);
    }
    __syncthreads();

    float acc0 = 0.f, acc1 = 0.f;
    const float* prow0 = &pl[wv * 2][0];       // wave-uniform -> LDS broadcast
    const float* prow1 = &pl[wv * 2 + 1][0];
    #pragma unroll 4
    for (int i = 0; i < 512; i += 4) {
        float4 p0 = *(const float4*)(prow0 + i);
        float4 p1 = *(const float4*)(prow1 + i);
        float w0 = wH[(i + 0) * 512 + o];      // lanes consecutive -> coalesced
        float w1 = wH[(i + 1) * 512 + o];
        float w2 = wH[(i + 2) * 512 + o];
        float w3 = wH[(i + 3) * 512 + o];
        acc0 = fmaf(p0.x, w0, acc0); acc0 = fmaf(p0.y, w1, acc0);
        acc0 = fmaf(p0.z, w2, acc0); acc0 = fmaf(p0.w, w3, acc0);
        acc1 = fmaf(p1.x, w0, acc1); acc1 = fmaf(p1.y, w1, acc1);
        acc1 = fmaf(p1.z, w2, acc1); acc1 = fmaf(p1.w, w3, acc1);
    }
    float hb  = bH[o];
    float wn  = wNeu[o];
    float v0  = fmaxf(acc0 + hb, 0.f) * wn;
    float v1  = fmaxf(acc1 + hb, 0.f) * wn;
    #pragma unroll
    for (int dlt = 1; dlt < 64; dlt <<= 1) {
        v0 += __shfl_xor(v0, dlt, 64);
        v1 += __shfl_xor(v1, dlt, 64);
    }
    if ((tid & 63) == 0) {
        int b0 = bg * 8 + wv * 2;
        float bias = (og == 0) ? wNeuB[0] : 0.f;
        atomicAdd(&out[b0],     0.5f * v0 + bias);
        atomicAdd(&out[b0 + 1], 0.5f * v1 + bias);
    }
}

extern "C" void kernel_launch(void* const* d_in, const int* in_sizes, int n_in,
                              void* d_out, int out_size, void* d_ws, size_t ws_size,
                              hipStream_t stream) {
    const float* x        = (const float*)d_in[0];
    const float* wConv    = (const float*)d_in[1];
    const float* wRect    = (const float*)d_in[2];
    const float* wHidden  = (const float*)d_in[3];
    const float* wHidBias = (const float*)d_in[4];
    const float* wNeu     = (const float*)d_in[5];
    const float* wNeuBias = (const float*)d_in[6];
    float* out  = (float*)d_out;
    (void)d_ws; (void)ws_size;                  // workspace unused

    hipMemsetAsync(d_out, 0, 256 * sizeof(float), stream);
    conv_pool_kernel<<<256, 512, 0, stream>>>(x, wConv, wRect);
    mlp_kernel<<<256, 256, 0, stream>>>(wHidden, wHidBias, wNeu, wNeuBias, out);
}

// Round 8
// 122.038 us; speedup vs baseline: 1.0357x; 1.0357x over previous
//
#include <hip/hip_runtime.h>
#include <stdint.h>

#define CIN   4
#define LEN   2048
#define HN    256
#define GL    24
#define LOUT  2025          // LEN - GL + 1
#define XP    2080          // padded LDS row stride in halfwords (mult of 8, >= 2048+32)

typedef short  s16x8 __attribute__((ext_vector_type(8)));
typedef float  f32x4 __attribute__((ext_vector_type(4)));

// final pool buffer: [b][0..255]=maxPool, [b][256..511]=avgPool
__device__ float g_pool[256 * 512];            // 512 KB, fully overwritten each run

static __device__ __forceinline__ uint16_t f2bf(float f) {
    union { float f; uint32_t u; } v; v.f = f;
    uint32_t u = v.u;
    return (uint16_t)((u + 0x7FFFu + ((u >> 16) & 1u)) >> 16);   // RNE
}

// A-fragment = 4 consecutive dwords of a window register block (pure selection,
// zero VALU: even phases from copy0 window E, odd phases from copy1 window O).
#define SEL4(D, i) \
    ({ uint4 fu_ = {(D)[(i)], (D)[(i)+1], (D)[(i)+2], (D)[(i)+3]}; \
       __builtin_bit_cast(s16x8, fu_); })

// load one window j: 2x ds_read_b128 per ks from copy0 (E) and copy1 (O)
static __device__ __forceinline__ void loadW(
    uint32_t (&E)[3][8], uint32_t (&O)[3][8],
    const uint16_t* xs, const uint16_t* xs2, const int (&abase)[3], int j)
{
    #pragma unroll
    for (int ks = 0; ks < 3; ++ks) {
        const uint4 e0 = *(const uint4*)&xs [abase[ks] + 128 * j];
        const uint4 e1 = *(const uint4*)&xs [abase[ks] + 128 * j + 8];
        const uint4 o0 = *(const uint4*)&xs2[abase[ks] + 128 * j];
        const uint4 o1 = *(const uint4*)&xs2[abase[ks] + 128 * j + 8];
        E[ks][0]=e0.x; E[ks][1]=e0.y; E[ks][2]=e0.z; E[ks][3]=e0.w;
        E[ks][4]=e1.x; E[ks][5]=e1.y; E[ks][6]=e1.z; E[ks][7]=e1.w;
        O[ks][0]=o0.x; O[ks][1]=o0.y; O[ks][2]=o0.z; O[ks][3]=o0.w;
        O[ks][4]=o1.x; O[ks][5]=o1.y; O[ks][6]=o1.z; O[ks][7]=o1.w;
    }
}

// process one 128-position window: 8 phases x (3 K-steps x 2 node-subtiles),
// immediate relu-fold. tail (wave-uniform runtime) masks tpos >= 2025 at j==15.
// s_setprio(1) around the MFMA cluster: conv waves are barrier-free and
// independent (attn-like structure) -> scheduler favors MFMA-entering waves
// (T5 mechanism: +4-7% on independent-wave kernels, null only on lockstep).
static __device__ __forceinline__ void procW(
    const uint32_t (&E)[3][8], const uint32_t (&O)[3][8],
    const s16x8 (&bfrag)[2][3], const float (&negb)[2],
    bool tail, int q, float (&rawmax)[2], float (&sums)[2])
{
    const f32x4 fzero = {0.f, 0.f, 0.f, 0.f};
    #pragma unroll
    for (int p = 0; p < 8; ++p) {
        s16x8 a0, a1, a2;
        if ((p & 1) == 0) {
            a0 = SEL4(E[0], p/2); a1 = SEL4(E[1], p/2); a2 = SEL4(E[2], p/2);
        } else {
            a0 = SEL4(O[0], (p-1)/2); a1 = SEL4(O[1], (p-1)/2); a2 = SEL4(O[2], (p-1)/2);
        }
        __builtin_amdgcn_s_setprio(1);
        f32x4 acc0, acc1;
        acc0 = __builtin_amdgcn_mfma_f32_16x16x32_bf16(a0, bfrag[0][0], fzero, 0, 0, 0);
        acc1 = __builtin_amdgcn_mfma_f32_16x16x32_bf16(a0, bfrag[1][0], fzero, 0, 0, 0);
        acc0 = __builtin_amdgcn_mfma_f32_16x16x32_bf16(a1, bfrag[0][1], acc0, 0, 0, 0);
        acc1 = __builtin_amdgcn_mfma_f32_16x16x32_bf16(a1, bfrag[1][1], acc1, 0, 0, 0);
        acc0 = __builtin_amdgcn_mfma_f32_16x16x32_bf16(a2, bfrag[0][2], acc0, 0, 0, 0);
        acc1 = __builtin_amdgcn_mfma_f32_16x16x32_bf16(a2, bfrag[1][2], acc1, 0, 0, 0);
        __builtin_amdgcn_s_setprio(0);

        // maxPool = max(0, b + max_t raw) -> track raw max (no clamp needed)
        // avgPool uses t = max(raw, -b), summed in a small tree.
        if (!tail) {
            #pragma unroll
            for (int s = 0; s < 2; ++s) {
                const f32x4 a = (s == 0) ? acc0 : acc1;
                float t0 = fmaxf(a[0], negb[s]), t1 = fmaxf(a[1], negb[s]);
                float t2 = fmaxf(a[2], negb[s]), t3 = fmaxf(a[3], negb[s]);
                sums[s] += (t0 + t1) + (t2 + t3);
                rawmax[s] = fmaxf(fmaxf(rawmax[s], a[0]), a[1]);   // -> v_max3
                rawmax[s] = fmaxf(fmaxf(rawmax[s], a[2]), a[3]);
            }
        } else {                            // j==15: mask tpos >= 2025
            #pragma unroll
            for (int s = 0; s < 2; ++s) {
                const f32x4 a = (s == 0) ? acc0 : acc1;
                #pragma unroll
                for (int r = 0; r < 4; ++r) {
                    int tpos = p + 128 * 15 + 32 * q + 8 * r;
                    float t = (tpos < LOUT) ? fmaxf(a[r], negb[s])
                                            : negb[s];   // contributes exactly 0 after +b
                    sums[s]   += t;
                    rawmax[s]  = fmaxf(rawmax[s], t);
                }
            }
        }
    }
}

// ---------------------------------------------------------------------------
// Kernel 1: per-sample conv1d (bf16 MFMA) + bias/relu + max/avg pool, fused.
// grid = 256 blocks (1 sample), 512 threads = 8 waves; wave wid owns nodes
// [32wid, 32wid+32) for ALL 16 windows -> staging amortized fully, no combine.
// Residency is 2 waves/EU; amdgpu_waves_per_eu(2,2) pins the allocator to the
// matching 256-reg budget (r5 lesson: without the max, it shrinks+spills).
// ILP instead of TLP: (a) shifted LDS copy xs2[h]=x[h+1] makes odd-phase
// fragments register selections (removes all 48 alignbits/window from the
// critical path); (b) depth-1 window pipeline EA/OA <-> EB/OB so the next
// window's 12 ds_read_b128 issue under the current window's 48 MFMA + fold.
// Positions: t = 128j + 32q + 8r + p. Pooling is order-invariant -> exact.
// (This is the round-6 best-measured body + setprio; structure otherwise frozen.)
// ---------------------------------------------------------------------------
__global__ __launch_bounds__(512) __attribute__((amdgpu_waves_per_eu(2, 2)))
void conv_pool_kernel(
    const float* __restrict__ x, const float* __restrict__ wConv,
    const float* __restrict__ wRect)
{
    __shared__ uint16_t xs [CIN * XP + 8];     // copy0 (+pad for copy1 build)
    __shared__ uint16_t xs2[CIN * XP + 8];     // copy1: xs2[h] = x[h+1]

    const int tid  = threadIdx.x;
    const int b    = blockIdx.x;
    const int lane = tid & 63;
    const int wid  = tid >> 6;                 // 0..7 -> nodes 32wid..32wid+31
    const int n    = lane & 15;                // MFMA row (A) / col (B,C)
    const int q    = lane >> 4;                // quad 0..3

    // ---- stage x[b] -> LDS copy0 as bf16 (coalesced float4 loads) ----
    const float* xb = x + (size_t)b * (CIN * LEN);
    #pragma unroll
    for (int it = 0; it < 4; ++it) {
        int i = (tid + it * 512) * 4;          // 0..8188 step 4
        float4 v = *(const float4*)(xb + i);
        int c = i >> 11, off = i & 2047;
        uint64_t pk =  (uint64_t)f2bf(v.x)
                    | ((uint64_t)f2bf(v.y) << 16)
                    | ((uint64_t)f2bf(v.z) << 32)
                    | ((uint64_t)f2bf(v.w) << 48);
        *(uint64_t*)&xs[c * XP + off] = pk;
    }
    // zero the pad tail [2048, 2080) of each row (+ build-pad)
    if (tid < 64) {
        int c = tid >> 4, o = (tid & 15) * 2;
        *(uint32_t*)&xs[c * XP + 2048 + o] = 0u;
    }
    if (tid < 4) *(uint32_t*)&xs[CIN * XP + tid * 2] = 0u;   // pad dwords

    // ---- resident B fragments (weights) + bias, straight from global ----
    s16x8 bfrag[2][3];
    float negb[2];
    #pragma unroll
    for (int s = 0; s < 2; ++s) {
        int h = wid * 32 + s * 16 + n;
        negb[s] = -wRect[h];
        #pragma unroll
        for (int ks = 0; ks < 3; ++ks) {
            int jb = ks * 4 + q;
            const float* wp_ = wConv + h * (CIN * GL) + jb * 8;
            float4 w0 = *(const float4*)(wp_);
            float4 w1 = *(const float4*)(wp_ + 4);
            s16x8 f;
            f[0]=(short)f2bf(w0.x); f[1]=(short)f2bf(w0.y);
            f[2]=(short)f2bf(w0.z); f[3]=(short)f2bf(w0.w);
            f[4]=(short)f2bf(w1.x); f[5]=(short)f2bf(w1.y);
            f[6]=(short)f2bf(w1.z); f[7]=(short)f2bf(w1.w);
            bfrag[s][ks] = f;
        }
    }

    // per-lane A base (halfword index): all terms mult of 8 -> 16B aligned
    int abase[3];
    #pragma unroll
    for (int ks = 0; ks < 3; ++ks) {
        int jb = ks * 4 + q;
        int c = jb / 3, g0 = (jb % 3) * 8;
        abase[ks] = c * XP + g0 + 8 * n;
    }

    __syncthreads();

    // ---- build copy1 from copy0 in LDS: s1[k] = {x[2k+1], x[2k+2]} ----
    {
        const uint32_t* s0 = (const uint32_t*)xs;
        uint32_t*       s1 = (uint32_t*)xs2;
        #pragma unroll 1
        for (int g = tid; g < (CIN * XP) / 8; g += 512) {   // 1040 4-dword chunks
            uint4 a = *(const uint4*)&s0[4 * g];
            uint32_t nx = s0[4 * g + 4];                    // pad covers last chunk
            uint4 r;
            r.x = __builtin_amdgcn_alignbit(a.y, a.x, 16);
            r.y = __builtin_amdgcn_alignbit(a.z, a.y, 16);
            r.z = __builtin_amdgcn_alignbit(a.w, a.z, 16);
            r.w = __builtin_amdgcn_alignbit(nx,  a.w, 16);
            *(uint4*)&s1[4 * g] = r;
        }
    }
    __syncthreads();

    float rawmax[2] = {-1e30f, -1e30f};
    float sums[2]   = {0.f, 0.f};

    // ---- depth-1 pipelined 16-window loop (static EA/OA/EB/OB naming) ----
    uint32_t EA[3][8], OA[3][8], EB[3][8], OB[3][8];
    loadW(EA, OA, xs, xs2, abase, 0);
    #pragma unroll 1
    for (int jj = 0; jj < 16; jj += 2) {
        loadW(EB, OB, xs, xs2, abase, jj + 1);             // prefetch odd window
        procW(EA, OA, bfrag, negb, false, q, rawmax, sums);          // j = jj (<=14)
        loadW(EA, OA, xs, xs2, abase, (jj + 2 < 16) ? jj + 2 : 15);  // prefetch next even
        procW(EB, OB, bfrag, negb, (jj + 1 == 15), q, rawmax, sums); // j = jj+1
    }

    // ---- cross-quad reduce (lanes n, n+16, n+32, n+48) -> final pool ----
    #pragma unroll
    for (int s = 0; s < 2; ++s) {
        float m  = rawmax[s], sm = sums[s];
        m  = fmaxf(m, __shfl_xor(m, 16, 64));  sm += __shfl_xor(sm, 16, 64);
        m  = fmaxf(m, __shfl_xor(m, 32, 64));  sm += __shfl_xor(sm, 32, 64);
        if (q == 0) {
            int h = wid * 32 + s * 16 + n;     // this wave's exclusive nodes
            float bia = -negb[s];
            g_pool[(size_t)b * 512 + h]       = fmaxf(m + bia, 0.f);
            g_pool[(size_t)b * 512 + 256 + h] = (sm + 2048.f * bia) * (1.0f / 2025.0f);
        }
    }
}

// ---------------------------------------------------------------------------
// Kernel 2: fp32 MLP, no atomics, no memset.
// hid = relu(pool @ wH + bH); out = 0.5*hid@wNeu + wNeuBias.
// grid = 128 blocks x 512 threads: block bg owns samples {2bg, 2bg+1} FULLY.
// Wave wid = output-group og (64 hidden each); lane o = og*64+lane; per-lane
// inner loop identical to the round-6 proven mlp (2 samples per lane).
// og-partials combined in LDS -> exclusive store to out (memset eliminated).
// ---------------------------------------------------------------------------
__global__ __launch_bounds__(512, 2) void mlp_kernel(
    const float* __restrict__ wH, const float* __restrict__ bH,
    const float* __restrict__ wNeu, const float* __restrict__ wNeuB,
    float* __restrict__ out)
{
    __shared__ float pl[2][512];               // 4 KB: pool rows of both samples
    __shared__ float part[8][2];               // per-og partial dot for 2 samples

    const int tid  = threadIdx.x;
    const int bg   = blockIdx.x;               // sample pair {2bg, 2bg+1}
    const int lane = tid & 63;
    const int og   = tid >> 6;                 // wave id = output group 0..7
    const int o    = og * 64 + lane;           // hidden unit owned by this lane

    // ---- stage both pool rows (1024 floats, coalesced float4) ----
    if (tid < 256) {
        int i = tid * 4;
        *(float4*)&pl[0][i] = *(const float4*)(g_pool + (size_t)bg * 1024 + i);
    }
    __syncthreads();

    float acc0 = 0.f, acc1 = 0.f;
    const float* prow0 = &pl[0][0];            // wave-uniform -> LDS broadcast
    const float* prow1 = &pl[1][0];
    #pragma unroll 4
    for (int i = 0; i < 512; i += 4) {
        float4 p0 = *(const float4*)(prow0 + i);
        float4 p1 = *(const float4*)(prow1 + i);
        float w0 = wH[(i + 0) * 512 + o];      // lanes consecutive -> coalesced
        float w1 = wH[(i + 1) * 512 + o];
        float w2 = wH[(i + 2) * 512 + o];
        float w3 = wH[(i + 3) * 512 + o];
        acc0 = fmaf(p0.x, w0, acc0); acc0 = fmaf(p0.y, w1, acc0);
        acc0 = fmaf(p0.z, w2, acc0); acc0 = fmaf(p0.w, w3, acc0);
        acc1 = fmaf(p1.x, w0, acc1); acc1 = fmaf(p1.y, w1, acc1);
        acc1 = fmaf(p1.z, w2, acc1); acc1 = fmaf(p1.w, w3, acc1);
    }
    float hb  = bH[o];
    float wn  = wNeu[o];
    float v0  = fmaxf(acc0 + hb, 0.f) * wn;
    float v1  = fmaxf(acc1 + hb, 0.f) * wn;
    #pragma unroll
    for (int dlt = 1; dlt < 64; dlt <<= 1) {
        v0 += __shfl_xor(v0, dlt, 64);
        v1 += __shfl_xor(v1, dlt, 64);
    }
    if (lane == 0) { part[og][0] = v0; part[og][1] = v1; }
    __syncthreads();

    if (tid < 2) {                             // exclusive final store, no atomics
        float s = 0.f;
        #pragma unroll
        for (int g = 0; g < 8; ++g) s += part[g][tid];
        out[bg * 2 + tid] = 0.5f * s + wNeuB[0];
    }
}

extern "C" void kernel_launch(void* const* d_in, const int* in_sizes, int n_in,
                              void* d_out, int out_size, void* d_ws, size_t ws_size,
                              hipStream_t stream) {
    const float* x        = (const float*)d_in[0];
    const float* wConv    = (const float*)d_in[1];
    const float* wRect    = (const float*)d_in[2];
    const float* wHidden  = (const float*)d_in[3];
    const float* wHidBias = (const float*)d_in[4];
    const float* wNeu     = (const float*)d_in[5];
    const float* wNeuBias = (const float*)d_in[6];
    float* out  = (float*)d_out;
    (void)d_ws; (void)ws_size;                  // workspace unused

    conv_pool_kernel<<<256, 512, 0, stream>>>(x, wConv, wRect);
    mlp_kernel<<<128, 512, 0, stream>>>(wHidden, wHidBias, wNeu, wNeuBias, out);
}